// Round 15
// baseline (232.480 us; speedup 1.0000x reference)
//
#include <hip/hip_runtime.h>

#define NN   10000

typedef float f32x4 __attribute__((ext_vector_type(4)));
typedef short s16x8 __attribute__((ext_vector_type(8)));
typedef short s16x4 __attribute__((ext_vector_type(4)));

__device__ __forceinline__ unsigned int f2bf(float f) {
  unsigned int u = __float_as_uint(f);
  return (u + 0x7fffu + ((u >> 16) & 1u)) >> 16;   // RNE
}
__device__ __forceinline__ float bf2f(unsigned int h) {
  return __uint_as_float(h << 16);
}

__global__ void k_zero2(int* __restrict__ p0, int* __restrict__ p1, int n) {
  int i = blockIdx.x * blockDim.x + threadIdx.x;
  if (i < n) { p0[i] = 0; p1[i] = 0; }
}

__global__ void k_count(const int* __restrict__ dst, int E, int* __restrict__ cnt) {
  int i = blockIdx.x * blockDim.x + threadIdx.x;
  if (i < E) atomicAdd(&cnt[dst[i]], 1);
}

__global__ __launch_bounds__(256) void k_scan(const int* __restrict__ cnt, int n,
                                              int* __restrict__ offs, float* __restrict__ dinv) {
  __shared__ int part[256];
  int t = threadIdx.x;
  int chunk = (n + 255) / 256;
  int lo = t * chunk, hi = min(lo + chunk, n);
  int s = 0;
  for (int i = lo; i < hi; ++i) s += cnt[i];
  part[t] = s;
  __syncthreads();
  for (int d = 1; d < 256; d <<= 1) {
    int v = (t >= d) ? part[t - d] : 0;
    __syncthreads();
    part[t] += v;
    __syncthreads();
  }
  int run = (t == 0) ? 0 : part[t - 1];
  for (int i = lo; i < hi; ++i) {
    offs[i] = run;
    int c = cnt[i];
    run += c;
    dinv[i] = rsqrtf((float)(c + 1));   // +1 self-loop
  }
  if (t == 255) offs[n] = run;
}

__global__ void k_fill(const int* __restrict__ src, const int* __restrict__ dst, int E,
                       const int* __restrict__ offs, int* __restrict__ cur, int* __restrict__ csr) {
  int i = blockIdx.x * blockDim.x + threadIdx.x;
  if (i < E) {
    int d = dst[i];
    int p = atomicAdd(&cur[d], 1);
    csr[offs[d] + p] = src[i];
  }
}

// Both weights in one dispatch. W [512][N] fp32 -> WT [N][1024] bf16 (hi | lo residual).
__global__ void k_convw2(const float* __restrict__ W1, unsigned short* __restrict__ WT1,
                         const float* __restrict__ W2, unsigned short* __restrict__ WT2) {
  int i = blockIdx.x * blockDim.x + threadIdx.x;
  if (i < 512 * 512) {
    int k = i >> 9, n = i & 511;             // N = 512
    float f = W1[i];
    unsigned int hb = f2bf(f);
    WT1[(size_t)n * 1024 + k] = (unsigned short)hb;
    WT1[(size_t)n * 1024 + 512 + k] = (unsigned short)f2bf(f - bf2f(hb));
  } else if (i < 512 * 512 + 512 * 256) {
    int j = i - 512 * 512;
    int k = j >> 8, n = j & 255;             // N = 256
    float f = W2[j];
    unsigned int hb = f2bf(f);
    WT2[(size_t)n * 1024 + k] = (unsigned short)hb;
    WT2[(size_t)n * 1024 + 512 + k] = (unsigned short)f2bf(f - bf2f(hb));
  }
}

// MFMA GEMM, C (bf16) [M][N] = A[M][512] * W[512][N].  BM=128, BN=64, 4 waves (2x2).
// Wave tile 64m x 32n -> acc[4][2]. Same fragment/CD mappings & K-order as the
// verified 64x64 version (bit-identical output).
// ASPLIT=true:  A fp32, split on the fly -> 3 MFMA terms (AhWh, AhWl, AlWh)
// ASPLIT=false: A already bf16 (exact)   -> 2 MFMA terms (AWh, AWl)
template <bool ASPLIT>
__global__ __launch_bounds__(256) void k_gemm_mfma(
    const void* __restrict__ Ap, const unsigned short* __restrict__ WT,
    unsigned short* __restrict__ C, int M, int N, int NTN) {
  __shared__ short Wh[64 * 40], Wl[64 * 40], Ahs[128 * 40];
  __shared__ short Als[ASPLIT ? 128 * 40 : 8];

  // bijective XCD-chunk swizzle (m204 form)
  int nwg = gridDim.x;
  int q = nwg >> 3, r = nwg & 7;
  int xcd = blockIdx.x & 7, idx = blockIdx.x >> 3;
  int swz = (xcd < r ? xcd * (q + 1) : r * (q + 1) + (xcd - r) * q) + idx;
  int bn = (swz % NTN) * 64;
  int bm = (swz / NTN) * 128;

  int t = threadIdx.x;
  int wid = t >> 6, lane = t & 63;
  int wn = wid & 1, wm = wid >> 1;     // wave tile: 64m x 32n
  int lr = lane & 15, lg = lane >> 4;

  int wrow = t >> 2, kg8 = (t & 3) * 8;   // W staging: 64 rows x 32k (16B each)
  int arow = t >> 3, kc4 = (t & 7) * 4;   // A fp32 staging: 32 rows/pass x 8 float4, 4 passes
  int brow = t >> 2, kb8 = (t & 3) * 8;   // A bf16 staging: 64 rows/pass x 32k, 2 passes

  f32x4 acc[4][2];
  #pragma unroll
  for (int i = 0; i < 4; ++i)
    #pragma unroll
    for (int j = 0; j < 2; ++j) acc[i][j] = (f32x4){0.f, 0.f, 0.f, 0.f};

  const unsigned short* wbase = WT + (size_t)(bn + wrow) * 1024;

  for (int kk = 0; kk < 512; kk += 32) {
    __syncthreads();
    // stage W hi & lo tiles (bf16, pre-transposed: rows = n, contiguous k)
    *(s16x8*)&Wh[wrow * 40 + kg8] = *(const s16x8*)&wbase[kk + kg8];
    *(s16x8*)&Wl[wrow * 40 + kg8] = *(const s16x8*)&wbase[512 + kk + kg8];
    if (ASPLIT) {
      // stage A tile from fp32, converting -> bf16 hi + lo residual
      const float* A = (const float*)Ap;
      #pragma unroll
      for (int p = 0; p < 4; ++p) {
        int row = arow + p * 32;
        int grow = bm + row;
        float4 v = make_float4(0.f, 0.f, 0.f, 0.f);
        if (grow < M) v = *(const float4*)&A[(size_t)grow * 512 + kk + kc4];
        float fs[4] = {v.x, v.y, v.z, v.w};
        s16x4 hv, lv;
        #pragma unroll
        for (int j = 0; j < 4; ++j) {
          unsigned int hb = f2bf(fs[j]);
          hv[j] = (short)hb;
          lv[j] = (short)f2bf(fs[j] - bf2f(hb));
        }
        *(s16x4*)&Ahs[row * 40 + kc4] = hv;
        *(s16x4*)&Als[row * 40 + kc4] = lv;
      }
    } else {
      // stage A tile directly from bf16
      const unsigned short* Ab = (const unsigned short*)Ap;
      #pragma unroll
      for (int p = 0; p < 2; ++p) {
        int row = brow + p * 64;
        int grow = bm + row;
        s16x8 v = (s16x8){0, 0, 0, 0, 0, 0, 0, 0};
        if (grow < M) v = *(const s16x8*)&Ab[(size_t)grow * 512 + kk + kb8];
        *(s16x8*)&Ahs[row * 40 + kb8] = v;
      }
    }
    __syncthreads();

    // fragment loads: contiguous 8 bf16 in k per lane (row = lane&15, k = 8*(lane>>4)+j)
    s16x8 fwh[2], fwl[2], fah[4], fal[4];
    #pragma unroll
    for (int i = 0; i < 2; ++i) {
      int nr = wn * 32 + i * 16 + lr;
      fwh[i] = *(const s16x8*)&Wh[nr * 40 + lg * 8];
      fwl[i] = *(const s16x8*)&Wl[nr * 40 + lg * 8];
    }
    #pragma unroll
    for (int i = 0; i < 4; ++i) {
      int mr = wm * 64 + i * 16 + lr;
      fah[i] = *(const s16x8*)&Ahs[mr * 40 + lg * 8];
      if (ASPLIT) fal[i] = *(const s16x8*)&Als[mr * 40 + lg * 8];
    }
    #pragma unroll
    for (int mi = 0; mi < 4; ++mi)
      #pragma unroll
      for (int ni = 0; ni < 2; ++ni) {
        acc[mi][ni] = __builtin_amdgcn_mfma_f32_16x16x32_bf16(fwh[ni], fah[mi], acc[mi][ni], 0, 0, 0);
        acc[mi][ni] = __builtin_amdgcn_mfma_f32_16x16x32_bf16(fwl[ni], fah[mi], acc[mi][ni], 0, 0, 0);
        if (ASPLIT)
          acc[mi][ni] = __builtin_amdgcn_mfma_f32_16x16x32_bf16(fwh[ni], fal[mi], acc[mi][ni], 0, 0, 0);
      }
  }

  // D holds C^T tile: lane m = bm+.. + (lane&15), n = bn+.. + 4*(lane>>4) + reg.
  #pragma unroll
  for (int mi = 0; mi < 4; ++mi) {
    int m = bm + wm * 64 + mi * 16 + lr;
    if (m < M) {
      #pragma unroll
      for (int ni = 0; ni < 2; ++ni) {
        int n0 = bn + wn * 32 + ni * 16 + lg * 4;
        ushort4 cv;
        cv.x = (unsigned short)f2bf(acc[mi][ni][0]);
        cv.y = (unsigned short)f2bf(acc[mi][ni][1]);
        cv.z = (unsigned short)f2bf(acc[mi][ni][2]);
        cv.w = (unsigned short)f2bf(acc[mi][ni][3]);
        *(ushort4*)&C[(size_t)m * N + n0] = cv;
      }
    }
  }
}

// per-node gather aggregation over bf16 H:
// out[i] = dinv[i]*(sum_in dinv[s]*H[s] + dinv[i]*H[i]) + b  (+relu), out bf16 or fp32
template <int F, bool RELU, bool OUTBF16>
__global__ __launch_bounds__(256) void k_agg_bf(
    const unsigned short* __restrict__ H, const float* __restrict__ dinv,
    const int* __restrict__ offs, const int* __restrict__ csr,
    const float* __restrict__ bias, void* __restrict__ outp) {
  constexpr int FT = F / 8;       // feature threads (8 bf16 = 16B each)
  constexpr int EG = 256 / FT;    // edge-parallel groups (4 for F=512, 8 for F=256)
  __shared__ float red[256][8];
  int node = blockIdx.x;
  int t = threadIdx.x;
  int fc = t % FT;
  int eg = t / FT;
  int lo = offs[node], hi = offs[node + 1];
  float a[8];
  #pragma unroll
  for (int j = 0; j < 8; ++j) a[j] = 0.f;
  for (int e = lo + eg; e < hi; e += EG) {
    int s = csr[e];
    float w = dinv[s];
    s16x8 v = *(const s16x8*)&H[(size_t)s * F + fc * 8];
    #pragma unroll
    for (int j = 0; j < 8; ++j) a[j] += w * bf2f((unsigned short)v[j]);
  }
  #pragma unroll
  for (int j = 0; j < 8; ++j) red[t][j] = a[j];
  __syncthreads();
  if (eg == 0) {
    #pragma unroll
    for (int g = 1; g < EG; ++g)
      #pragma unroll
      for (int j = 0; j < 8; ++j) a[j] += red[g * FT + fc][j];
    float wd = dinv[node];
    s16x8 sv = *(const s16x8*)&H[(size_t)node * F + fc * 8];
    float o[8];
    #pragma unroll
    for (int j = 0; j < 8; ++j) {
      o[j] = wd * (a[j] + wd * bf2f((unsigned short)sv[j])) + bias[fc * 8 + j];
      if (RELU) o[j] = fmaxf(o[j], 0.f);
    }
    if (OUTBF16) {
      s16x8 hv;
      #pragma unroll
      for (int j = 0; j < 8; ++j) hv[j] = (short)f2bf(o[j]);
      *(s16x8*)&((unsigned short*)outp)[(size_t)node * F + fc * 8] = hv;
    } else {
      float* op = (float*)outp;
      *(float4*)&op[(size_t)node * F + fc * 8]     = make_float4(o[0], o[1], o[2], o[3]);
      *(float4*)&op[(size_t)node * F + fc * 8 + 4] = make_float4(o[4], o[5], o[6], o[7]);
    }
  }
}

extern "C" void kernel_launch(void* const* d_in, const int* in_sizes, int n_in,
                              void* d_out, int out_size, void* d_ws, size_t ws_size,
                              hipStream_t stream) {
  (void)n_in; (void)out_size; (void)ws_size;
  const float* x  = (const float*)d_in[0];
  const int*   ei = (const int*)d_in[1];
  const float* W1 = (const float*)d_in[2];
  const float* b1 = (const float*)d_in[3];
  const float* W2 = (const float*)d_in[4];
  const float* b2 = (const float*)d_in[5];
  float* out = (float*)d_out;

  int E = in_sizes[1] / 2;
  const int* src = ei;
  const int* dst = ei + E;

  char* w = (char*)d_ws;
  float*          dinv = (float*)(w);
  int*            cnt  = (int*)(w + 65536);
  int*            cur  = (int*)(w + 131072);
  int*            offs = (int*)(w + 196608);
  int*            csr  = (int*)(w + 262144);               // 640 KB
  unsigned short* WT1  = (unsigned short*)(w + 1048576);   // 1 MB
  unsigned short* WT2  = (unsigned short*)(w + 2097152);   // 0.5 MB
  unsigned short* h1   = (unsigned short*)(w + 3145728);   // 10.24 MB (bf16)
  unsigned short* a1   = (unsigned short*)(w + 14680064);  // 10.24 MB (bf16)
  unsigned short* h2   = (unsigned short*)(w + 26214400);  // 5.12 MB (bf16), ends ~31.3 MB

  k_zero2<<<(NN + 255) / 256, 256, 0, stream>>>(cnt, cur, NN);
  k_count<<<(E + 255) / 256, 256, 0, stream>>>(dst, E, cnt);
  k_scan<<<1, 256, 0, stream>>>(cnt, NN, offs, dinv);
  k_fill<<<(E + 255) / 256, 256, 0, stream>>>(src, dst, E, offs, cur, csr);
  k_convw2<<<(512 * 512 + 512 * 256 + 255) / 256, 256, 0, stream>>>(W1, WT1, W2, WT2);

  int ntm = (NN + 127) / 128;   // 79
  k_gemm_mfma<true><<<8 * ntm, 256, 0, stream>>>(x, WT1, h1, NN, 512, 8);
  k_agg_bf<512, true, true><<<NN, 256, 0, stream>>>(h1, dinv, offs, csr, b1, a1);
  k_gemm_mfma<false><<<4 * ntm, 256, 0, stream>>>(a1, WT2, h2, NN, 256, 4);
  k_agg_bf<256, false, false><<<NN, 256, 0, stream>>>(h2, dinv, offs, csr, b2, out);
}

// Round 16
// 220.850 us; speedup vs baseline: 1.0527x; 1.0527x over previous
//
#include <hip/hip_runtime.h>

#define NN   10000

typedef float f32x4 __attribute__((ext_vector_type(4)));
typedef short s16x8 __attribute__((ext_vector_type(8)));

__device__ __forceinline__ unsigned int f2bf(float f) {
  unsigned int u = __float_as_uint(f);
  return (u + 0x7fffu + ((u >> 16) & 1u)) >> 16;   // RNE
}
__device__ __forceinline__ float bf2f(unsigned int h) {
  return __uint_as_float(h << 16);
}

__global__ void k_zero2(int* __restrict__ p0, int* __restrict__ p1, int n) {
  int i = blockIdx.x * blockDim.x + threadIdx.x;
  if (i < n) { p0[i] = 0; p1[i] = 0; }
}

__global__ void k_count(const int* __restrict__ dst, int E, int* __restrict__ cnt) {
  int i = blockIdx.x * blockDim.x + threadIdx.x;
  if (i < E) atomicAdd(&cnt[dst[i]], 1);
}

__global__ __launch_bounds__(256) void k_scan(const int* __restrict__ cnt, int n,
                                              int* __restrict__ offs, float* __restrict__ dinv) {
  __shared__ int part[256];
  int t = threadIdx.x;
  int chunk = (n + 255) / 256;
  int lo = t * chunk, hi = min(lo + chunk, n);
  int s = 0;
  for (int i = lo; i < hi; ++i) s += cnt[i];
  part[t] = s;
  __syncthreads();
  for (int d = 1; d < 256; d <<= 1) {
    int v = (t >= d) ? part[t - d] : 0;
    __syncthreads();
    part[t] += v;
    __syncthreads();
  }
  int run = (t == 0) ? 0 : part[t - 1];
  for (int i = lo; i < hi; ++i) {
    offs[i] = run;
    int c = cnt[i];
    run += c;
    dinv[i] = rsqrtf((float)(c + 1));   // +1 self-loop
  }
  if (t == 255) offs[n] = run;
}

__global__ void k_fill(const int* __restrict__ src, const int* __restrict__ dst, int E,
                       const int* __restrict__ offs, int* __restrict__ cur, int* __restrict__ csr) {
  int i = blockIdx.x * blockDim.x + threadIdx.x;
  if (i < E) {
    int d = dst[i];
    int p = atomicAdd(&cur[d], 1);
    csr[offs[d] + p] = src[i];
  }
}

// One dispatch: W1,W2 -> transposed hi|lo bf16; X -> Xh/Xl bf16 split (hoisted out of gemm1).
__global__ void k_conv_all(const float* __restrict__ W1, unsigned short* __restrict__ WT1,
                           const float* __restrict__ W2, unsigned short* __restrict__ WT2,
                           const float* __restrict__ X, unsigned short* __restrict__ Xh,
                           unsigned short* __restrict__ Xl) {
  int i = blockIdx.x * blockDim.x + threadIdx.x;
  if (i < 512 * 512) {
    int k = i >> 9, n = i & 511;             // W1: N = 512
    float f = W1[i];
    unsigned int hb = f2bf(f);
    WT1[(size_t)n * 1024 + k] = (unsigned short)hb;
    WT1[(size_t)n * 1024 + 512 + k] = (unsigned short)f2bf(f - bf2f(hb));
  } else if (i < 512 * 512 + 512 * 256) {
    int j = i - 512 * 512;
    int k = j >> 8, n = j & 255;             // W2: N = 256
    float f = W2[j];
    unsigned int hb = f2bf(f);
    WT2[(size_t)n * 1024 + k] = (unsigned short)hb;
    WT2[(size_t)n * 1024 + 512 + k] = (unsigned short)f2bf(f - bf2f(hb));
  } else {
    int j = i - (512 * 512 + 512 * 256);
    if (j < NN * 512) {
      float f = X[j];
      unsigned int hb = f2bf(f);
      Xh[j] = (unsigned short)hb;
      Xl[j] = (unsigned short)f2bf(f - bf2f(hb));
    }
  }
}

// MFMA GEMM, C (bf16) [M][N] = A[M][512] * W[512][N].  64x64 tile, 4 waves (2x2) —
// the round-11-verified geometry (1256/628 blocks keeps ~5 blocks/CU; 128-tile regressed).
// A given as pre-split bf16 (Ah, and Al residual if HASLO). Bit-identical K-order.
// HASLO=true: 3 MFMA terms (AhWh, AhWl... order: Wh*Ah, Wl*Ah, Wh*Al). false: 2 terms.
template <bool HASLO>
__global__ __launch_bounds__(256) void k_gemm_mfma(
    const unsigned short* __restrict__ Ah, const unsigned short* __restrict__ Al,
    const unsigned short* __restrict__ WT, unsigned short* __restrict__ C,
    int M, int N, int NTN) {
  __shared__ short Wh[64 * 40], Wl[64 * 40], Ahs[64 * 40];
  __shared__ short Als[HASLO ? 64 * 40 : 8];

  // bijective XCD-chunk swizzle (m204 form)
  int nwg = gridDim.x;
  int q = nwg >> 3, r = nwg & 7;
  int xcd = blockIdx.x & 7, idx = blockIdx.x >> 3;
  int swz = (xcd < r ? xcd * (q + 1) : r * (q + 1) + (xcd - r) * q) + idx;
  int bn = (swz % NTN) * 64;
  int bm = (swz / NTN) * 64;

  int t = threadIdx.x;
  int wid = t >> 6, lane = t & 63;
  int wn = wid & 1, wm = wid >> 1;     // wave tile: 32n x 32m
  int lr = lane & 15, lg = lane >> 4;

  int wrow = t >> 2, kg8 = (t & 3) * 8;   // staging: 64 rows x 32k, 16B per thread

  f32x4 acc[2][2];
  #pragma unroll
  for (int i = 0; i < 2; ++i)
    #pragma unroll
    for (int j = 0; j < 2; ++j) acc[i][j] = (f32x4){0.f, 0.f, 0.f, 0.f};

  const unsigned short* wbase = WT + (size_t)(bn + wrow) * 1024;
  int agrow = bm + wrow;
  bool aok = agrow < M;
  const unsigned short* ahbase = Ah + (size_t)agrow * 512;
  const unsigned short* albase = HASLO ? Al + (size_t)agrow * 512 : nullptr;

  for (int kk = 0; kk < 512; kk += 32) {
    __syncthreads();
    // stage W hi & lo tiles (bf16, pre-transposed: rows = n, contiguous k)
    *(s16x8*)&Wh[wrow * 40 + kg8] = *(const s16x8*)&wbase[kk + kg8];
    *(s16x8*)&Wl[wrow * 40 + kg8] = *(const s16x8*)&wbase[512 + kk + kg8];
    // stage A hi (and lo) tiles, already bf16
    s16x8 av = (s16x8){0, 0, 0, 0, 0, 0, 0, 0};
    if (aok) av = *(const s16x8*)&ahbase[kk + kg8];
    *(s16x8*)&Ahs[wrow * 40 + kg8] = av;
    if (HASLO) {
      s16x8 lv = (s16x8){0, 0, 0, 0, 0, 0, 0, 0};
      if (aok) lv = *(const s16x8*)&albase[kk + kg8];
      *(s16x8*)&Als[wrow * 40 + kg8] = lv;
    }
    __syncthreads();

    // fragment loads: contiguous 8 bf16 in k per lane (row = lane&15, k = 8*(lane>>4)+j)
    s16x8 fwh[2], fwl[2], fah[2], fal[2];
    #pragma unroll
    for (int i = 0; i < 2; ++i) {
      int nr = wn * 32 + i * 16 + lr;
      int mr = wm * 32 + i * 16 + lr;
      fwh[i] = *(const s16x8*)&Wh[nr * 40 + lg * 8];
      fwl[i] = *(const s16x8*)&Wl[nr * 40 + lg * 8];
      fah[i] = *(const s16x8*)&Ahs[mr * 40 + lg * 8];
      if (HASLO) fal[i] = *(const s16x8*)&Als[mr * 40 + lg * 8];
    }
    #pragma unroll
    for (int mi = 0; mi < 2; ++mi)
      #pragma unroll
      for (int ni = 0; ni < 2; ++ni) {
        acc[mi][ni] = __builtin_amdgcn_mfma_f32_16x16x32_bf16(fwh[ni], fah[mi], acc[mi][ni], 0, 0, 0);
        acc[mi][ni] = __builtin_amdgcn_mfma_f32_16x16x32_bf16(fwl[ni], fah[mi], acc[mi][ni], 0, 0, 0);
        if (HASLO)
          acc[mi][ni] = __builtin_amdgcn_mfma_f32_16x16x32_bf16(fwh[ni], fal[mi], acc[mi][ni], 0, 0, 0);
      }
  }

  // D holds C^T tile: lane m = bm+.. + (lane&15), n = bn+.. + 4*(lane>>4) + reg.
  #pragma unroll
  for (int mi = 0; mi < 2; ++mi) {
    int m = bm + wm * 32 + mi * 16 + lr;
    if (m < M) {
      #pragma unroll
      for (int ni = 0; ni < 2; ++ni) {
        int n0 = bn + wn * 32 + ni * 16 + lg * 4;
        ushort4 cv;
        cv.x = (unsigned short)f2bf(acc[mi][ni][0]);
        cv.y = (unsigned short)f2bf(acc[mi][ni][1]);
        cv.z = (unsigned short)f2bf(acc[mi][ni][2]);
        cv.w = (unsigned short)f2bf(acc[mi][ni][3]);
        *(ushort4*)&C[(size_t)m * N + n0] = cv;
      }
    }
  }
}

// per-node gather aggregation over bf16 H:
// out[i] = dinv[i]*(sum_in dinv[s]*H[s] + dinv[i]*H[i]) + b  (+relu), out bf16 or fp32
template <int F, bool RELU, bool OUTBF16>
__global__ __launch_bounds__(256) void k_agg_bf(
    const unsigned short* __restrict__ H, const float* __restrict__ dinv,
    const int* __restrict__ offs, const int* __restrict__ csr,
    const float* __restrict__ bias, void* __restrict__ outp) {
  constexpr int FT = F / 8;       // feature threads (8 bf16 = 16B each)
  constexpr int EG = 256 / FT;    // edge-parallel groups (4 for F=512, 8 for F=256)
  __shared__ float red[256][8];
  int node = blockIdx.x;
  int t = threadIdx.x;
  int fc = t % FT;
  int eg = t / FT;
  int lo = offs[node], hi = offs[node + 1];
  float a[8];
  #pragma unroll
  for (int j = 0; j < 8; ++j) a[j] = 0.f;
  for (int e = lo + eg; e < hi; e += EG) {
    int s = csr[e];
    float w = dinv[s];
    s16x8 v = *(const s16x8*)&H[(size_t)s * F + fc * 8];
    #pragma unroll
    for (int j = 0; j < 8; ++j) a[j] += w * bf2f((unsigned short)v[j]);
  }
  #pragma unroll
  for (int j = 0; j < 8; ++j) red[t][j] = a[j];
  __syncthreads();
  if (eg == 0) {
    #pragma unroll
    for (int g = 1; g < EG; ++g)
      #pragma unroll
      for (int j = 0; j < 8; ++j) a[j] += red[g * FT + fc][j];
    float wd = dinv[node];
    s16x8 sv = *(const s16x8*)&H[(size_t)node * F + fc * 8];
    float o[8];
    #pragma unroll
    for (int j = 0; j < 8; ++j) {
      o[j] = wd * (a[j] + wd * bf2f((unsigned short)sv[j])) + bias[fc * 8 + j];
      if (RELU) o[j] = fmaxf(o[j], 0.f);
    }
    if (OUTBF16) {
      s16x8 hv;
      #pragma unroll
      for (int j = 0; j < 8; ++j) hv[j] = (short)f2bf(o[j]);
      *(s16x8*)&((unsigned short*)outp)[(size_t)node * F + fc * 8] = hv;
    } else {
      float* op = (float*)outp;
      *(float4*)&op[(size_t)node * F + fc * 8]     = make_float4(o[0], o[1], o[2], o[3]);
      *(float4*)&op[(size_t)node * F + fc * 8 + 4] = make_float4(o[4], o[5], o[6], o[7]);
    }
  }
}

extern "C" void kernel_launch(void* const* d_in, const int* in_sizes, int n_in,
                              void* d_out, int out_size, void* d_ws, size_t ws_size,
                              hipStream_t stream) {
  (void)n_in; (void)out_size; (void)ws_size;
  const float* x  = (const float*)d_in[0];
  const int*   ei = (const int*)d_in[1];
  const float* W1 = (const float*)d_in[2];
  const float* b1 = (const float*)d_in[3];
  const float* W2 = (const float*)d_in[4];
  const float* b2 = (const float*)d_in[5];
  float* out = (float*)d_out;

  int E = in_sizes[1] / 2;
  const int* src = ei;
  const int* dst = ei + E;

  char* w = (char*)d_ws;
  float*          dinv = (float*)(w);
  int*            cnt  = (int*)(w + 65536);
  int*            cur  = (int*)(w + 131072);
  int*            offs = (int*)(w + 196608);
  int*            csr  = (int*)(w + 262144);               // 640 KB
  unsigned short* WT1  = (unsigned short*)(w + 1048576);   // 1 MB
  unsigned short* WT2  = (unsigned short*)(w + 2097152);   // 0.5 MB
  unsigned short* h1   = (unsigned short*)(w + 3145728);   // 10.24 MB (bf16)
  unsigned short* a1   = (unsigned short*)(w + 14680064);  // 10.24 MB (bf16)
  unsigned short* h2   = (unsigned short*)(w + 26214400);  // 5.12 MB (bf16)
  unsigned short* Xh   = (unsigned short*)(w + 31457280);  // 10.24 MB (bf16)
  unsigned short* Xl   = (unsigned short*)(w + 41943040);  // 10.24 MB (bf16), ends ~52.2 MB

  k_zero2<<<(NN + 255) / 256, 256, 0, stream>>>(cnt, cur, NN);
  k_count<<<(E + 255) / 256, 256, 0, stream>>>(dst, E, cnt);
  k_scan<<<1, 256, 0, stream>>>(cnt, NN, offs, dinv);
  k_fill<<<(E + 255) / 256, 256, 0, stream>>>(src, dst, E, offs, cur, csr);

  int nconv = 512 * 512 + 512 * 256 + NN * 512;
  k_conv_all<<<(nconv + 255) / 256, 256, 0, stream>>>(W1, WT1, W2, WT2, x, Xh, Xl);

  int ntm = (NN + 63) / 64;   // 157
  k_gemm_mfma<true><<<8 * ntm, 256, 0, stream>>>(Xh, Xl, WT1, h1, NN, 512, 8);
  k_agg_bf<512, true, true><<<NN, 256, 0, stream>>>(h1, dinv, offs, csr, b1, a1);
  k_gemm_mfma<false><<<4 * ntm, 256, 0, stream>>>(a1, nullptr, WT2, h2, NN, 256, 4);
  k_agg_bf<256, false, false><<<NN, 256, 0, stream>>>(h2, dinv, offs, csr, b2, out);
}